// Round 5
// baseline (753.897 us; speedup 1.0000x reference)
//
#include <hip/hip_runtime.h>
#include <math.h>

// Problem constants (fixed by reference)
constexpr int Bc   = 8;
constexpr int Nc   = 512;
constexpr int Dc   = 512;
constexpr int HHc  = 8;     // half the heads
constexpr int DHc  = 32;
constexpr int DEGc = 16;
constexpr int Ec   = Bc * Nc * DEGc;          // 65536 edges
constexpr float LN2   = 0.69314718055994530942f;
constexpr float SCALE = 0.17677669529663688110f;  // 1/sqrt(32)

typedef unsigned short ushort_t;
typedef __attribute__((ext_vector_type(8))) short short8;
typedef __attribute__((ext_vector_type(4))) float f32x4;

// softplus(x)-ln2 via native v_exp_f32/v_log_f32 (~7 VALU inst vs ~22 for
// libm log1pf+expf; rel err ~2^-21 << bf16 quantum)
__device__ __forceinline__ float splus_m_ln2(float x) {
    float t = __expf(-fabsf(x));
    return fmaxf(x, 0.0f) + __logf(1.0f + t) - LN2;
}

__device__ __forceinline__ ushort_t f2bf(float x) {
    union { float f; unsigned int u; } v; v.f = x;
    unsigned int r = (v.u + 0x7fffu + ((v.u >> 16) & 1u)) >> 16;   // RNE
    return (ushort_t)r;
}
__device__ __forceinline__ float bf2f(ushort_t x) {
    union { unsigned int u; float f; } v; v.u = ((unsigned int)x) << 16;
    return v.f;
}

__device__ __forceinline__ void gload16(const ushort_t* g, ushort_t* l) {
    __builtin_amdgcn_global_load_lds(
        (const __attribute__((address_space(1))) void*)g,
        (__attribute__((address_space(3))) void*)l, 16, 0, 0);
}

// ---------------------------------------------------------------------------
// bf16 MFMA GEMM: C[M,NOUT] = act(A[M,K] @ Bt^T + bias)
// 2-phase double-buffered schedule (T3 minimum recipe):
//   prologue: STAGE(buf0, t=0); vmcnt(0); barrier
//   loop t:   STAGE(buf^1, t+1); COMPUTE(buf); vmcnt(0); barrier; flip
// One barrier per K-step; the vmcnt drain lands AFTER the MFMA phase so the
// prefetch latency hides under compute (vs the old stage->drain->compute).
// A: bf16 [M][K] row-major (or GATHER: rows = concat(out[b,i], out[b,j]))
// Bt: bf16 [NOUT][K] (pre-transposed weight)
// OUTMODE: 0 = fp32 out, 1 = bf16 out, 2 = fp32 out + bf16 copy to Cout2
// 128x128 block tile, BK=32, 256 threads = 4 waves in 2x2, 4x4 MFMA frags/wave.
// LDS [2][128*32] bf16 unpadded — required by global_load_lds lane order.
// ---------------------------------------------------------------------------
template<int ACT, int GATHER, int OUTMODE, int K, int NOUT>
__global__ __launch_bounds__(256) void gemm_mfma(
    const ushort_t* __restrict__ A, const ushort_t* __restrict__ Bt,
    const float* __restrict__ bias, void* __restrict__ Cout,
    ushort_t* __restrict__ Cout2,
    const int* __restrict__ pb, const int* __restrict__ pi,
    const int* __restrict__ pj)
{
    __shared__ ushort_t As[2][128 * 32];
    __shared__ ushort_t Bs[2][128 * 32];

    const int t    = threadIdx.x;
    const int lane = t & 63;
    const int w    = t >> 6;
    const int wy   = w >> 1, wx = w & 1;
    const int rowBase = blockIdx.y * 128;
    const int colBase = blockIdx.x * 128;

    // staging: thread t loads row (r*64 + t>>2), k-chunk (t&3)*8
    const int sm0 = t >> 2;
    const int kch = (t & 3) * 8;

    const ushort_t *a0i, *a0j = nullptr, *a1i, *a1j = nullptr;
    if (GATHER) {
        const int e0 = rowBase + sm0, e1 = rowBase + 64 + sm0;
        a0i = A + ((size_t)(pb[e0] * Nc + pi[e0])) * Dc;
        a0j = A + ((size_t)(pb[e0] * Nc + pj[e0])) * Dc;
        a1i = A + ((size_t)(pb[e1] * Nc + pi[e1])) * Dc;
        a1j = A + ((size_t)(pb[e1] * Nc + pj[e1])) * Dc;
    } else {
        a0i = A + (size_t)(rowBase + sm0) * K;
        a1i = A + (size_t)(rowBase + 64 + sm0) * K;
    }
    const ushort_t* b0 = Bt + (size_t)(colBase + sm0) * K;
    const ushort_t* b1 = Bt + (size_t)(colBase + 64 + sm0) * K;

    // wave-uniform LDS staging bases (elements; HW adds lane*16B)
    const int soff0 = w * 64 * 8;
    const int soff1 = (256 + w * 64) * 8;

    f32x4 acc[4][4];
    const f32x4 fz = {0.f, 0.f, 0.f, 0.f};
    #pragma unroll
    for (int i = 0; i < 4; ++i)
        #pragma unroll
        for (int j = 0; j < 4; ++j) acc[i][j] = fz;

    const int c16 = lane & 15;
    const int q16 = lane >> 4;

    auto STAGE = [&](int s, int kb) {
        const int k0 = kb << 5;
        const ushort_t *pa0, *pa1;
        if constexpr (GATHER) {
            if (kb < (Dc >> 5)) { pa0 = a0i + k0; pa1 = a1i + k0; }
            else                { pa0 = a0j + (k0 - Dc); pa1 = a1j + (k0 - Dc); }
        } else { pa0 = a0i + k0; pa1 = a1i + k0; }
        gload16(pa0 + kch, &As[s][soff0]);
        gload16(pa1 + kch, &As[s][soff1]);
        gload16(b0 + k0 + kch, &Bs[s][soff0]);
        gload16(b1 + k0 + kch, &Bs[s][soff1]);
    };

    auto COMPUTE = [&](int s) {
        short8 af[4], bfr[4];
        #pragma unroll
        for (int i = 0; i < 4; ++i)
            af[i] = *(const short8*)&As[s][(size_t)((wy * 64 + i * 16 + c16) * 32 + q16 * 8)];
        #pragma unroll
        for (int j = 0; j < 4; ++j)
            bfr[j] = *(const short8*)&Bs[s][(size_t)((wx * 64 + j * 16 + c16) * 32 + q16 * 8)];
        #pragma unroll
        for (int i = 0; i < 4; ++i)
            #pragma unroll
            for (int j = 0; j < 4; ++j)
                acc[i][j] = __builtin_amdgcn_mfma_f32_16x16x32_bf16(af[i], bfr[j], acc[i][j], 0, 0, 0);
    };

    constexpr int NKB = K >> 5;
    STAGE(0, 0);
    asm volatile("s_waitcnt vmcnt(0)" ::: "memory");
    __syncthreads();
    int cur = 0;
    #pragma unroll 2
    for (int kb = 0; kb < NKB; ++kb) {
        if (kb + 1 < NKB) STAGE(cur ^ 1, kb + 1);   // prefetch next tile
        COMPUTE(cur);                                // hides prefetch latency
        asm volatile("s_waitcnt vmcnt(0)" ::: "memory");
        __syncthreads();
        cur ^= 1;
    }

    // Epilogue: C/D layout col=lane&15, row=(lane>>4)*4+reg  [m89-verified]
    #pragma unroll
    for (int j = 0; j < 4; ++j) {
        const int col = colBase + wx * 64 + j * 16 + c16;
        const float bv = bias[col];
        #pragma unroll
        for (int i = 0; i < 4; ++i) {
            const int row0 = rowBase + wy * 64 + i * 16 + q16 * 4;
            #pragma unroll
            for (int r = 0; r < 4; ++r) {
                float v = acc[i][j][r] + bv;
                if (ACT) v = splus_m_ln2(v);
                const size_t idx = (size_t)(row0 + r) * NOUT + col;
                if (OUTMODE == 1) {
                    ((ushort_t*)Cout)[idx] = f2bf(v);
                } else {
                    ((float*)Cout)[idx] = v;
                    if (OUTMODE == 2) Cout2[idx] = f2bf(v);
                }
            }
        }
    }
}

// ---------------------------------------------------------------------------
// Conversion helpers
// ---------------------------------------------------------------------------
__global__ __launch_bounds__(256) void cvt_f32_bf16(
    const float* __restrict__ src, ushort_t* __restrict__ dst)
{
    const int i = blockIdx.x * 256 + threadIdx.x;
    float4 v = ((const float4*)src)[i];
    ushort4 o;
    o.x = f2bf(v.x); o.y = f2bf(v.y); o.z = f2bf(v.z); o.w = f2bf(v.w);
    ((ushort4*)dst)[i] = o;
}

// Wt[n][k] = bf16(W[k][n]); block (32,8), one 32x32 tile per block
__global__ void transpose_cvt(const float* __restrict__ W, ushort_t* __restrict__ Wt,
                              int K, int NOUT)
{
    __shared__ float tile[32][33];
    const int k0 = blockIdx.x * 32, n0 = blockIdx.y * 32;
    #pragma unroll
    for (int r = 0; r < 4; ++r)
        tile[threadIdx.y + r * 8][threadIdx.x] =
            W[(size_t)(k0 + threadIdx.y + r * 8) * NOUT + n0 + threadIdx.x];
    __syncthreads();
    #pragma unroll
    for (int r = 0; r < 4; ++r)
        Wt[(size_t)(n0 + threadIdx.y + r * 8) * K + k0 + threadIdx.x] =
            f2bf(tile[threadIdx.x][threadIdx.y + r * 8]);
}

// ---------------------------------------------------------------------------
// Global attention, tiled (fp32):
// block = 256 threads, one (b, h, 16-row q-tile).  grid = (N/16, B*HH).
// K streamed through LDS in 4 chunks of 128 rows (stride 36 pad), full score
// row S[16][512] (stride 516 pad) in LDS, 2-pass softmax per 16-lane row
// group, then V streamed through the same LDS chunk buffer for PV.
// LDS = (8256 + 4608 + 576)*4 = 53.8 KB -> 2 blocks/CU.
// ctx layout: ctx[b,n, h*64+0:32]=global head h ; [h*64+32:64]=local head h
// ---------------------------------------------------------------------------
__global__ __launch_bounds__(256) void global_attn(
    const float* __restrict__ qp, const float* __restrict__ kp,
    const float* __restrict__ vp, float* __restrict__ ctx,
    float* __restrict__ top)
{
    __shared__ float S[16 * 516];     // scores, row stride 516 (pad 4)
    __shared__ float KV[128 * 36];    // K or V chunk, row stride 36 (pad 4)
    __shared__ float Qs[16 * 36];     // scaled Q tile

    const int t  = threadIdx.x;
    const int bh = blockIdx.y;
    const int b  = bh >> 3;
    const int h  = bh & (HHc - 1);
    const int q0 = blockIdx.x << 4;   // first q row of tile

    const size_t hb = ((size_t)b * Nc) * Dc + h * DHc;   // head base

    // ---- stage Q tile (pre-scaled) ----
    if (t < 128) {
        const int qr = t >> 3, off = (t & 7) << 2;
        float4 v = *(const float4*)&qp[hb + (size_t)(q0 + qr) * Dc + off];
        float* dst = &Qs[qr * 36 + off];
        dst[0] = v.x * SCALE; dst[1] = v.y * SCALE;
        dst[2] = v.z * SCALE; dst[3] = v.w * SCALE;
    }
    __syncthreads();

    const int q  = t >> 4;    // 0..15  (q row within tile; 16 lanes per row)
    const int lj = t & 15;    // lane within row group

    float qreg[32];
    #pragma unroll
    for (int d4 = 0; d4 < 8; ++d4) {
        float4 v = *(const float4*)&Qs[q * 36 + (d4 << 2)];
        qreg[(d4 << 2) + 0] = v.x; qreg[(d4 << 2) + 1] = v.y;
        qreg[(d4 << 2) + 2] = v.z; qreg[(d4 << 2) + 3] = v.w;
    }

    // ---- phase 1: scores S[q][k] over 4 K-chunks of 128 rows ----
    const int kr  = t >> 1;           // staging row 0..127
    const int koff = (t & 1) << 4;    // staging half-row offset
    for (int c = 0; c < 4; ++c) {
        __syncthreads();   // previous chunk's reads of KV complete
        {
            const float* src = &kp[hb + (size_t)((c << 7) + kr) * Dc + koff];
            float* dst = &KV[kr * 36 + koff];
            *(float4*)&dst[0]  = *(const float4*)&src[0];
            *(float4*)&dst[4]  = *(const float4*)&src[4];
            *(float4*)&dst[8]  = *(const float4*)&src[8];
            *(float4*)&dst[12] = *(const float4*)&src[12];
        }
        __syncthreads();
        #pragma unroll
        for (int i = 0; i < 8; ++i) {
            const int k = lj + (i << 4);
            const float* krow = &KV[k * 36];
            float s0 = 0.f, s1 = 0.f, s2 = 0.f, s3 = 0.f;
            #pragma unroll
            for (int d4 = 0; d4 < 8; ++d4) {
                float4 kv4 = *(const float4*)&krow[d4 << 2];
                s0 += qreg[(d4 << 2) + 0] * kv4.x;
                s1 += qreg[(d4 << 2) + 1] * kv4.y;
                s2 += qreg[(d4 << 2) + 2] * kv4.z;
                s3 += qreg[(d4 << 2) + 3] * kv4.w;
            }
            S[q * 516 + (c << 7) + k] = (s0 + s1) + (s2 + s3);
        }
    }
    __syncthreads();   // all scores visible to all threads

    // ---- top write (h==0): raw scaled scores, before exp overwrites S ----
    if (h == 0) {
        float* trow = top + ((size_t)(b * Nc + q0)) * Nc;   // 16 rows, contiguous
        #pragma unroll
        for (int i = 0; i < 8; ++i) {
            const int f = (i << 8) + t;       // float4 index 0..2047
            const int l = f << 2;             // linear float index
            const int r = l >> 9, k = l & 511;
            *(float4*)&trow[l] = *(const float4*)&S[r * 516 + k];
        }
        __syncthreads();   // top reads done before exp pass overwrites S
    }

    // ---- softmax per row (16 lanes per row, interleaved scan) ----
    const int sbase = q * 516;
    float m = -1e30f;
    #pragma unroll
    for (int i = 0; i < 32; ++i)
        m = fmaxf(m, S[sbase + lj + (i << 4)]);
    #pragma unroll
    for (int off = 1; off < 16; off <<= 1)
        m = fmaxf(m, __shfl_xor(m, off, 64));
    float l = 0.f;
    #pragma unroll
    for (int i = 0; i < 32; ++i) {
        const int idx = sbase + lj + (i << 4);
        const float e = __expf(S[idx] - m);
        S[idx] = e;
        l += e;
    }
    #pragma unroll
    for (int off = 1; off < 16; off <<= 1)
        l += __shfl_xor(l, off, 64);
    const float inv = 1.0f / l;
    // (no barrier needed: S row q is only read below by the 16 lanes that
    //  wrote it — same wave)

    // ---- phase 2: PV over 4 V-chunks; thread owns (q, d-pair) ----
    const int d2 = lj;                // output dims d2*2, d2*2+1
    float a00 = 0.f, a01 = 0.f, a10 = 0.f, a11 = 0.f;
    for (int c = 0; c < 4; ++c) {
        __syncthreads();   // phase-1 (or prev chunk) reads of KV complete
        {
            const float* src = &vp[hb + (size_t)((c << 7) + kr) * Dc + koff];
            float* dst = &KV[kr * 36 + koff];
            *(float4*)&dst[0]  = *(const float4*)&src[0];
            *(float4*)&dst[4]  = *(const float4*)&src[4];
            *(float4*)&dst[8]  = *(const float4*)&src[8];
            *(float4*)&dst[12] = *(const float4*)&src[12];
        }
        __syncthreads();
        const float* srow = &S[sbase + (c << 7)];
        #pragma unroll 8
        for (int k = 0; k < 128; k += 2) {
            const float w0 = srow[k];
            const float w1 = srow[k + 1];
            const float2 v0 = *(const float2*)&KV[k * 36 + (d2 << 1)];
            const float2 v1 = *(const float2*)&KV[(k + 1) * 36 + (d2 << 1)];
            a00 = fmaf(w0, v0.x, a00); a01 = fmaf(w0, v0.y, a01);
            a10 = fmaf(w1, v1.x, a10); a11 = fmaf(w1, v1.y, a11);
        }
    }
    float2 o;
    o.x = (a00 + a10) * inv;
    o.y = (a01 + a11) * inv;
    *(float2*)&ctx[((size_t)(b * Nc + q0 + q)) * Dc + (h << 6) + (d2 << 1)] = o;
}

// ---------------------------------------------------------------------------
// Local attention (ef2 bf16)
// ---------------------------------------------------------------------------
__global__ __launch_bounds__(256) void local_scores(
    const float* __restrict__ qp, const float* __restrict__ kp,
    const ushort_t* __restrict__ ef2,
    const int* __restrict__ pb, const int* __restrict__ pi,
    const int* __restrict__ pj, float* __restrict__ sl)
{
    const int gid = blockIdx.x * 256 + threadIdx.x;   // e*8 + h
    const int h = gid & 7;
    const int e = gid >> 3;
    const int b = pb[e], i = pi[e], j = pj[e];
    const float* qrow = qp  + ((size_t)(b * Nc + i)) * Dc + (HHc + h) * DHc;
    const float* krow = kp  + ((size_t)(b * Nc + j)) * Dc + (HHc + h) * DHc;
    const ushort_t* erow = ef2 + (size_t)e * 256 + h * DHc;
    float s = 0.f;
    #pragma unroll
    for (int d4 = 0; d4 < 8; ++d4) {
        float4 qv = *(const float4*)&qrow[d4 << 2];
        float4 kv = *(const float4*)&krow[d4 << 2];
        ushort4 ev = *(const ushort4*)&erow[d4 << 2];
        s += qv.x * kv.x * bf2f(ev.x) + qv.y * kv.y * bf2f(ev.y)
           + qv.z * kv.z * bf2f(ev.z) + qv.w * kv.w * bf2f(ev.w);
    }
    sl[gid] = s * SCALE;
}

__global__ __launch_bounds__(256) void local_softmax(float* __restrict__ sl)
{
    const int gid = blockIdx.x * 256 + threadIdx.x;   // bi*8 + h
    const int h  = gid & 7;
    const int bi = gid >> 3;
    float s[DEGc];
    float m = -1e30f;
    #pragma unroll
    for (int tt = 0; tt < DEGc; ++tt) {
        s[tt] = sl[(size_t)(bi * DEGc + tt) * 8 + h];
        m = fmaxf(m, s[tt]);
    }
    float l = 0.f;
    #pragma unroll
    for (int tt = 0; tt < DEGc; ++tt) { s[tt] = expf(s[tt] - m); l += s[tt]; }
    const float inv = 1.0f / l;
    #pragma unroll
    for (int tt = 0; tt < DEGc; ++tt)
        sl[(size_t)(bi * DEGc + tt) * 8 + h] = s[tt] * inv;
}

__global__ __launch_bounds__(256) void local_ctx_kernel(
    const float* __restrict__ vp, const float* __restrict__ sl,
    const int* __restrict__ pj, float* __restrict__ ctx)
{
    const int bi = blockIdx.x;            // b*N + i
    const int t  = threadIdx.x;
    const int d  = t & 31;
    const int h  = t >> 5;
    __shared__ float a_s[DEGc][8];
    __shared__ int   jrow[DEGc];
    const int b = bi >> 9;
    if (t < DEGc) jrow[t] = pj[bi * DEGc + t];
    if (t < DEGc * 8) a_s[t >> 3][t & 7] = sl[(size_t)bi * (DEGc * 8) + t];
    __syncthreads();
    float acc = 0.f;
    #pragma unroll
    for (int tt = 0; tt < DEGc; ++tt) {
        const int j = jrow[tt];
        acc += a_s[tt][h] * vp[((size_t)(b * Nc + j)) * Dc + (HHc + h) * DHc + d];
    }
    ctx[(size_t)bi * Dc + (h << 6) + 32 + d] = acc;
}

// ---------------------------------------------------------------------------
extern "C" void kernel_launch(void* const* d_in, const int* in_sizes, int n_in,
                              void* d_out, int out_size, void* d_ws, size_t ws_size,
                              hipStream_t stream) {
    const float* key   = (const float*)d_in[0];
    const float* value = (const float*)d_in[1];
    const float* query = (const float*)d_in[2];
    const float* edge_feature = (const float*)d_in[4];
    const int* pb = (const int*)d_in[5];
    const int* pi = (const int*)d_in[6];
    const int* pj = (const int*)d_in[7];
    const float* Wq = (const float*)d_in[8];  const float* bq = (const float*)d_in[9];
    const float* Wk = (const float*)d_in[10]; const float* bk = (const float*)d_in[11];
    const float* Wv = (const float*)d_in[12]; const float* bv = (const float*)d_in[13];
    const float* Wo = (const float*)d_in[14]; const float* bo = (const float*)d_in[15];
    const float* We1 = (const float*)d_in[16]; const float* be1 = (const float*)d_in[17];
    const float* We2 = (const float*)d_in[18]; const float* be2 = (const float*)d_in[19];
    const float* Wu1 = (const float*)d_in[20]; const float* bu1 = (const float*)d_in[21];
    const float* Wu2 = (const float*)d_in[22]; const float* bu2 = (const float*)d_in[23];

    float* out  = (float*)d_out;          // (B,N,D)
    float* top  = out + 2097152;          // (B,N,N)
    float* eupd = out + 4194304;          // (E,D)

    float* qp  = (float*)d_ws;            // 2097152 f
    float* kp  = qp + 2097152;
    float* vp  = kp + 2097152;
    float* ctx = vp + 2097152;
    float* sl  = ctx + 2097152;           // 524288 f
    ushort_t* ef2b  = (ushort_t*)(sl + 524288);   // E*256
    ushort_t* efb   = ef2b + 16777216;            // E*512
    ushort_t* hidb  = efb + 33554432;             // E*512
    ushort_t* outb  = hidb + 33554432;            // 2097152
    ushort_t* wt_e1 = outb + 2097152;             // 512*512
    ushort_t* wt_e2 = wt_e1 + 262144;             // 256*512
    ushort_t* wt_u1 = wt_e2 + 131072;             // 512*1024
    ushort_t* wt_u2 = wt_u1 + 524288;             // 512*512

    // Aliased into efb's region — efb is dead after the first edge-MLP GEMM,
    // and the edge path is launched FIRST (stream-serialized), so no overlap.
    ushort_t* wt_q = efb;                 // 262144
    ushort_t* wt_k = wt_q + 262144;
    ushort_t* wt_v = wt_k + 262144;
    ushort_t* wt_o = wt_v + 262144;
    ushort_t* qb   = wt_o + 262144;       // 2097152
    ushort_t* kb   = qb + 2097152;
    ushort_t* vb   = kb + 2097152;
    ushort_t* ctxb = vb + 2097152;        // ends at efb+9437184 < 33554432 ok

    dim3 blk(256);
    dim3 tblk(32, 8);

    // ---- Edge path first (frees efb for aliasing) ----
    transpose_cvt<<<dim3(16, 16), tblk, 0, stream>>>(We1, wt_e1, 512, 512);
    transpose_cvt<<<dim3(16, 8),  tblk, 0, stream>>>(We2, wt_e2, 512, 256);
    transpose_cvt<<<dim3(32, 16), tblk, 0, stream>>>(Wu1, wt_u1, 1024, 512);
    transpose_cvt<<<dim3(16, 16), tblk, 0, stream>>>(Wu2, wt_u2, 512, 512);
    cvt_f32_bf16<<<32768, blk, 0, stream>>>(edge_feature, efb);

    // Edge MLP (bf16 MFMA): hid = act(ef @ We1 + be1); ef2 = hid @ We2 + be2
    gemm_mfma<1, 0, 1, 512, 512><<<dim3(4, 512), blk, 0, stream>>>(efb, wt_e1, be1, hidb, nullptr, nullptr, nullptr, nullptr);
    gemm_mfma<0, 0, 1, 512, 256><<<dim3(2, 512), blk, 0, stream>>>(hidb, wt_e2, be2, ef2b, nullptr, nullptr, nullptr, nullptr);
    // efb dead from here on.

    // ---- QKV projections on the matrix pipe ----
    transpose_cvt<<<dim3(16, 16), tblk, 0, stream>>>(Wq, wt_q, 512, 512);
    transpose_cvt<<<dim3(16, 16), tblk, 0, stream>>>(Wk, wt_k, 512, 512);
    transpose_cvt<<<dim3(16, 16), tblk, 0, stream>>>(Wv, wt_v, 512, 512);
    transpose_cvt<<<dim3(16, 16), tblk, 0, stream>>>(Wo, wt_o, 512, 512);
    cvt_f32_bf16<<<2048, blk, 0, stream>>>(query, qb);
    cvt_f32_bf16<<<2048, blk, 0, stream>>>(key,   kb);
    cvt_f32_bf16<<<2048, blk, 0, stream>>>(value, vb);

    gemm_mfma<0, 0, 0, 512, 512><<<dim3(4, 32), blk, 0, stream>>>(qb, wt_q, bq, qp, nullptr, nullptr, nullptr, nullptr);
    gemm_mfma<0, 0, 0, 512, 512><<<dim3(4, 32), blk, 0, stream>>>(kb, wt_k, bk, kp, nullptr, nullptr, nullptr, nullptr);
    gemm_mfma<0, 0, 0, 512, 512><<<dim3(4, 32), blk, 0, stream>>>(vb, wt_v, bv, vp, nullptr, nullptr, nullptr, nullptr);

    // ---- Attention ----
    global_attn<<<dim3(32, 64), blk, 0, stream>>>(qp, kp, vp, ctx, top);
    local_scores<<<2048, blk, 0, stream>>>(qp, kp, ef2b, pb, pi, pj, sl);
    local_softmax<<<128, blk, 0, stream>>>(sl);
    local_ctx_kernel<<<4096, blk, 0, stream>>>(vp, sl, pj, ctx);

    // ---- Output projection (bf16 MFMA, writes fp32 out + bf16 outb) ----
    cvt_f32_bf16<<<2048, blk, 0, stream>>>(ctx, ctxb);
    gemm_mfma<0, 0, 2, 512, 512><<<dim3(4, 32), blk, 0, stream>>>(ctxb, wt_o, bo, out, outb, nullptr, nullptr, nullptr);

    // ---- Edge update MLP (bf16 MFMA, A gathered from outb, K=1024) ----
    gemm_mfma<1, 1, 1, 1024, 512><<<dim3(4, 512), blk, 0, stream>>>(outb, wt_u1, bu1, hidb, nullptr, pb, pi, pj);
    gemm_mfma<0, 0, 0, 512, 512><<<dim3(4, 512), blk, 0, stream>>>(hidb, wt_u2, bu2, eupd, nullptr, nullptr, nullptr, nullptr);
}

// Round 6
// 696.931 us; speedup vs baseline: 1.0817x; 1.0817x over previous
//
#include <hip/hip_runtime.h>
#include <math.h>

// Problem constants (fixed by reference)
constexpr int Bc   = 8;
constexpr int Nc   = 512;
constexpr int Dc   = 512;
constexpr int HHc  = 8;     // half the heads
constexpr int DHc  = 32;
constexpr int DEGc = 16;
constexpr int Ec   = Bc * Nc * DEGc;          // 65536 edges
constexpr float LN2   = 0.69314718055994530942f;
constexpr float SCALE = 0.17677669529663688110f;  // 1/sqrt(32)

typedef unsigned short ushort_t;
typedef __attribute__((ext_vector_type(8))) short short8;
typedef __attribute__((ext_vector_type(4))) float f32x4;

// softplus(x)-ln2 via native v_exp_f32/v_log_f32 (~7 VALU inst)
__device__ __forceinline__ float splus_m_ln2(float x) {
    float t = __expf(-fabsf(x));
    return fmaxf(x, 0.0f) + __logf(1.0f + t) - LN2;
}

__device__ __forceinline__ ushort_t f2bf(float x) {
    union { float f; unsigned int u; } v; v.f = x;
    unsigned int r = (v.u + 0x7fffu + ((v.u >> 16) & 1u)) >> 16;   // RNE
    return (ushort_t)r;
}
__device__ __forceinline__ float bf2f(ushort_t x) {
    union { unsigned int u; float f; } v; v.u = ((unsigned int)x) << 16;
    return v.f;
}

__device__ __forceinline__ void gload16(const ushort_t* g, ushort_t* l) {
    __builtin_amdgcn_global_load_lds(
        (const __attribute__((address_space(1))) void*)g,
        (__attribute__((address_space(3))) void*)l, 16, 0, 0);
}

// ---------------------------------------------------------------------------
// bf16 MFMA GEMM: C[M,NOUT] = act(A[M,K] @ Bt^T + bias)
// 3-buffer pipeline with COUNTED vmcnt (T4): two stages always in flight;
// in-loop wait is vmcnt(4) (next stage's 4 loads stay flying across the raw
// s_barrier) — never drain-0 until the epilogue peel. One barrier per K-step.
// T2 both-sides XOR swizzle: LDS[row][c8] holds global[row][c8 ^ (row&3)]
// (achieved by pre-swizzling each lane's GLOBAL chunk — LDS dest stays
// linear per global_load_lds rules); reads XOR the chunk with (row&3).
// Breaks the 8-way ds_read_b128 bank conflict of the row-major [128][32] tile.
// OUTMODE: 0 = fp32 out, 1 = bf16 out, 2 = fp32 out + bf16 copy to Cout2
// BIAS: 0 = skip bias add (for the Wu1-split partial GEMMs)
// 128x128 tile, BK=32, 256 threads = 4 waves 2x2, 4x4 frags/wave. LDS 48 KB.
// ---------------------------------------------------------------------------
template<int ACT, int GATHER, int OUTMODE, int K, int NOUT, int BIAS = 1>
__global__ __launch_bounds__(256) void gemm_mfma(
    const ushort_t* __restrict__ A, const ushort_t* __restrict__ Bt,
    const float* __restrict__ bias, void* __restrict__ Cout,
    ushort_t* __restrict__ Cout2,
    const int* __restrict__ pb, const int* __restrict__ pi,
    const int* __restrict__ pj)
{
    __shared__ ushort_t As[3][128 * 32];
    __shared__ ushort_t Bs[3][128 * 32];

    const int t    = threadIdx.x;
    const int lane = t & 63;
    const int w    = t >> 6;
    const int wy   = w >> 1, wx = w & 1;
    const int rowBase = blockIdx.y * 128;
    const int colBase = blockIdx.x * 128;

    // staging: thread t covers row (t>>2), chunk (t&3); source chunk is
    // XOR-swizzled by row&3 = (t>>2)&3 so the linear LDS write lands swizzled.
    const int sm0  = t >> 2;
    const int kchs = (((t & 3) ^ ((t >> 2) & 3)) << 3);   // element offset

    const ushort_t *a0i, *a0j = nullptr, *a1i, *a1j = nullptr;
    if (GATHER) {
        const int e0 = rowBase + sm0, e1 = rowBase + 64 + sm0;
        a0i = A + ((size_t)(pb[e0] * Nc + pi[e0])) * Dc;
        a0j = A + ((size_t)(pb[e0] * Nc + pj[e0])) * Dc;
        a1i = A + ((size_t)(pb[e1] * Nc + pi[e1])) * Dc;
        a1j = A + ((size_t)(pb[e1] * Nc + pj[e1])) * Dc;
    } else {
        a0i = A + (size_t)(rowBase + sm0) * K;
        a1i = A + (size_t)(rowBase + 64 + sm0) * K;
    }
    const ushort_t* b0 = Bt + (size_t)(colBase + sm0) * K;
    const ushort_t* b1 = Bt + (size_t)(colBase + 64 + sm0) * K;

    // wave-uniform LDS staging bases (elements; HW adds lane*16B)
    const int soff0 = w * 64 * 8;
    const int soff1 = (256 + w * 64) * 8;

    f32x4 acc[4][4];
    const f32x4 fz = {0.f, 0.f, 0.f, 0.f};
    #pragma unroll
    for (int i = 0; i < 4; ++i)
        #pragma unroll
        for (int j = 0; j < 4; ++j) acc[i][j] = fz;

    const int c16 = lane & 15;
    const int q16 = lane >> 4;
    const int rdo = ((q16 ^ (c16 & 3)) << 3);   // swizzled read chunk offset

    auto STAGE = [&](int s, int kb) {
        const int k0 = kb << 5;
        const ushort_t *pa0, *pa1;
        if constexpr (GATHER) {
            if (kb < (Dc >> 5)) { pa0 = a0i + k0; pa1 = a1i + k0; }
            else                { pa0 = a0j + (k0 - Dc); pa1 = a1j + (k0 - Dc); }
        } else { pa0 = a0i + k0; pa1 = a1i + k0; }
        gload16(pa0 + kchs, &As[s][soff0]);
        gload16(pa1 + kchs, &As[s][soff1]);
        gload16(b0 + k0 + kchs, &Bs[s][soff0]);
        gload16(b1 + k0 + kchs, &Bs[s][soff1]);
    };

    auto COMPUTE = [&](int s) {
        short8 af[4], bfr[4];
        #pragma unroll
        for (int i = 0; i < 4; ++i)
            af[i] = *(const short8*)&As[s][(size_t)((wy * 64 + i * 16 + c16) * 32 + rdo)];
        #pragma unroll
        for (int j = 0; j < 4; ++j)
            bfr[j] = *(const short8*)&Bs[s][(size_t)((wx * 64 + j * 16 + c16) * 32 + rdo)];
        #pragma unroll
        for (int i = 0; i < 4; ++i)
            #pragma unroll
            for (int j = 0; j < 4; ++j)
                acc[i][j] = __builtin_amdgcn_mfma_f32_16x16x32_bf16(af[i], bfr[j], acc[i][j], 0, 0, 0);
    };

    constexpr int NKB = K >> 5;   // >= 2 for all instantiations
    STAGE(0, 0);
    STAGE(1, 1);
    for (int kb = 0; kb < NKB - 2; ++kb) {
        // in flight: stages kb, kb+1 (8 loads). Wait only the oldest 4.
        asm volatile("s_waitcnt vmcnt(4)" ::: "memory");
        __builtin_amdgcn_s_barrier();
        STAGE((kb + 2) % 3, kb + 2);   // buf was read in iter kb-1; barrier above = WAR safe
        COMPUTE(kb % 3);
    }
    asm volatile("s_waitcnt vmcnt(4)" ::: "memory");
    __builtin_amdgcn_s_barrier();
    COMPUTE((NKB - 2) % 3);
    asm volatile("s_waitcnt vmcnt(0)" ::: "memory");
    __builtin_amdgcn_s_barrier();
    COMPUTE((NKB - 1) % 3);

    // Epilogue: C/D layout col=lane&15, row=(lane>>4)*4+reg  [m89-verified]
    #pragma unroll
    for (int j = 0; j < 4; ++j) {
        const int col = colBase + wx * 64 + j * 16 + c16;
        const float bv = BIAS ? bias[col] : 0.0f;
        #pragma unroll
        for (int i = 0; i < 4; ++i) {
            const int row0 = rowBase + wy * 64 + i * 16 + q16 * 4;
            #pragma unroll
            for (int r = 0; r < 4; ++r) {
                float v = acc[i][j][r] + bv;
                if (ACT) v = splus_m_ln2(v);
                const size_t idx = (size_t)(row0 + r) * NOUT + col;
                if (OUTMODE == 1) {
                    ((ushort_t*)Cout)[idx] = f2bf(v);
                } else {
                    ((float*)Cout)[idx] = v;
                    if (OUTMODE == 2) Cout2[idx] = f2bf(v);
                }
            }
        }
    }
}

// ---------------------------------------------------------------------------
// Edge-update fuse: hid[e] = bf16(softplus(P1[b,i] + P2[b,j] + bu1) - ln2)
// Replaces the 68.7-GFLOP gathered u1 GEMM with two 2.1-GFLOP GEMMs + this
// streaming pass (matmul linearity over the concat[out_i,out_j] rows).
// 2 edges per 256-thread block; float4 per thread.
// ---------------------------------------------------------------------------
__global__ __launch_bounds__(256) void edge_u1_fuse(
    const float* __restrict__ P1, const float* __restrict__ P2,
    const float* __restrict__ bias,
    const int* __restrict__ pb, const int* __restrict__ pi,
    const int* __restrict__ pj, ushort_t* __restrict__ hid)
{
    const int e  = blockIdx.x * 2 + (threadIdx.x >> 7);
    const int c4 = (threadIdx.x & 127) << 2;
    const int b = pb[e], i = pi[e], j = pj[e];
    const float4 a = *(const float4*)&P1[((size_t)(b * Nc + i)) * Dc + c4];
    const float4 d = *(const float4*)&P2[((size_t)(b * Nc + j)) * Dc + c4];
    const float4 bv = *(const float4*)&bias[c4];
    ushort4 o;
    o.x = f2bf(splus_m_ln2(a.x + d.x + bv.x));
    o.y = f2bf(splus_m_ln2(a.y + d.y + bv.y));
    o.z = f2bf(splus_m_ln2(a.z + d.z + bv.z));
    o.w = f2bf(splus_m_ln2(a.w + d.w + bv.w));
    *(ushort4*)&hid[(size_t)e * Dc + c4] = o;
}

// ---------------------------------------------------------------------------
// Conversion helpers
// ---------------------------------------------------------------------------
__global__ __launch_bounds__(256) void cvt_f32_bf16(
    const float* __restrict__ src, ushort_t* __restrict__ dst)
{
    const int i = blockIdx.x * 256 + threadIdx.x;
    float4 v = ((const float4*)src)[i];
    ushort4 o;
    o.x = f2bf(v.x); o.y = f2bf(v.y); o.z = f2bf(v.z); o.w = f2bf(v.w);
    ((ushort4*)dst)[i] = o;
}

// Wt[n][k] = bf16(W[k][n]); block (32,8), one 32x32 tile per block
__global__ void transpose_cvt(const float* __restrict__ W, ushort_t* __restrict__ Wt,
                              int K, int NOUT)
{
    __shared__ float tile[32][33];
    const int k0 = blockIdx.x * 32, n0 = blockIdx.y * 32;
    #pragma unroll
    for (int r = 0; r < 4; ++r)
        tile[threadIdx.y + r * 8][threadIdx.x] =
            W[(size_t)(k0 + threadIdx.y + r * 8) * NOUT + n0 + threadIdx.x];
    __syncthreads();
    #pragma unroll
    for (int r = 0; r < 4; ++r)
        Wt[(size_t)(n0 + threadIdx.y + r * 8) * K + k0 + threadIdx.x] =
            f2bf(tile[threadIdx.x][threadIdx.y + r * 8]);
}

// ---------------------------------------------------------------------------
// Global attention, tiled (fp32):
// block = 256 threads, one (b, h, 16-row q-tile).  grid = (N/16, B*HH).
// ---------------------------------------------------------------------------
__global__ __launch_bounds__(256) void global_attn(
    const float* __restrict__ qp, const float* __restrict__ kp,
    const float* __restrict__ vp, float* __restrict__ ctx,
    float* __restrict__ top)
{
    __shared__ float S[16 * 516];     // scores, row stride 516 (pad 4)
    __shared__ float KV[128 * 36];    // K or V chunk, row stride 36 (pad 4)
    __shared__ float Qs[16 * 36];     // scaled Q tile

    const int t  = threadIdx.x;
    const int bh = blockIdx.y;
    const int b  = bh >> 3;
    const int h  = bh & (HHc - 1);
    const int q0 = blockIdx.x << 4;   // first q row of tile

    const size_t hb = ((size_t)b * Nc) * Dc + h * DHc;   // head base

    // ---- stage Q tile (pre-scaled) ----
    if (t < 128) {
        const int qr = t >> 3, off = (t & 7) << 2;
        float4 v = *(const float4*)&qp[hb + (size_t)(q0 + qr) * Dc + off];
        float* dst = &Qs[qr * 36 + off];
        dst[0] = v.x * SCALE; dst[1] = v.y * SCALE;
        dst[2] = v.z * SCALE; dst[3] = v.w * SCALE;
    }
    __syncthreads();

    const int q  = t >> 4;    // 0..15  (q row within tile; 16 lanes per row)
    const int lj = t & 15;    // lane within row group

    float qreg[32];
    #pragma unroll
    for (int d4 = 0; d4 < 8; ++d4) {
        float4 v = *(const float4*)&Qs[q * 36 + (d4 << 2)];
        qreg[(d4 << 2) + 0] = v.x; qreg[(d4 << 2) + 1] = v.y;
        qreg[(d4 << 2) + 2] = v.z; qreg[(d4 << 2) + 3] = v.w;
    }

    // ---- phase 1: scores S[q][k] over 4 K-chunks of 128 rows ----
    const int kr  = t >> 1;           // staging row 0..127
    const int koff = (t & 1) << 4;    // staging half-row offset
    for (int c = 0; c < 4; ++c) {
        __syncthreads();   // previous chunk's reads of KV complete
        {
            const float* src = &kp[hb + (size_t)((c << 7) + kr) * Dc + koff];
            float* dst = &KV[kr * 36 + koff];
            *(float4*)&dst[0]  = *(const float4*)&src[0];
            *(float4*)&dst[4]  = *(const float4*)&src[4];
            *(float4*)&dst[8]  = *(const float4*)&src[8];
            *(float4*)&dst[12] = *(const float4*)&src[12];
        }
        __syncthreads();
        #pragma unroll
        for (int i = 0; i < 8; ++i) {
            const int k = lj + (i << 4);
            const float* krow = &KV[k * 36];
            float s0 = 0.f, s1 = 0.f, s2 = 0.f, s3 = 0.f;
            #pragma unroll
            for (int d4 = 0; d4 < 8; ++d4) {
                float4 kv4 = *(const float4*)&krow[d4 << 2];
                s0 += qreg[(d4 << 2) + 0] * kv4.x;
                s1 += qreg[(d4 << 2) + 1] * kv4.y;
                s2 += qreg[(d4 << 2) + 2] * kv4.z;
                s3 += qreg[(d4 << 2) + 3] * kv4.w;
            }
            S[q * 516 + (c << 7) + k] = (s0 + s1) + (s2 + s3);
        }
    }
    __syncthreads();   // all scores visible to all threads

    // ---- top write (h==0): raw scaled scores, before exp overwrites S ----
    if (h == 0) {
        float* trow = top + ((size_t)(b * Nc + q0)) * Nc;   // 16 rows, contiguous
        #pragma unroll
        for (int i = 0; i < 8; ++i) {
            const int f = (i << 8) + t;       // float4 index 0..2047
            const int l = f << 2;             // linear float index
            const int r = l >> 9, k = l & 511;
            *(float4*)&trow[l] = *(const float4*)&S[r * 516 + k];
        }
        __syncthreads();   // top reads done before exp pass overwrites S
    }

    // ---- softmax per row (16 lanes per row, interleaved scan) ----
    const int sbase = q * 516;
    float m = -1e30f;
    #pragma unroll
    for (int i = 0; i < 32; ++i)
        m = fmaxf(m, S[sbase + lj + (i << 4)]);
    #pragma unroll
    for (int off = 1; off < 16; off <<= 1)
        m = fmaxf(m, __shfl_xor(m, off, 64));
    float l = 0.f;
    #pragma unroll
    for (int i = 0; i < 32; ++i) {
        const int idx = sbase + lj + (i << 4);
        const float e = __expf(S[idx] - m);
        S[idx] = e;
        l += e;
    }
    #pragma unroll
    for (int off = 1; off < 16; off <<= 1)
        l += __shfl_xor(l, off, 64);
    const float inv = 1.0f / l;

    // ---- phase 2: PV over 4 V-chunks; thread owns (q, d-pair) ----
    const int d2 = lj;                // output dims d2*2, d2*2+1
    float a00 = 0.f, a01 = 0.f, a10 = 0.f, a11 = 0.f;
    for (int c = 0; c < 4; ++c) {
        __syncthreads();   // phase-1 (or prev chunk) reads of KV complete
        {
            const float* src = &vp[hb + (size_t)((c << 7) + kr) * Dc + koff];
            float* dst = &KV[kr * 36 + koff];
            *(float4*)&dst[0]  = *(const float4*)&src[0];
            *(float4*)&dst[4]  = *(const float4*)&src[4];
            *(float4*)&dst[8]  = *(const float4*)&src[8];
            *(float4*)&dst[12] = *(const float4*)&src[12];
        }
        __syncthreads();
        const float* srow = &S[sbase + (c << 7)];
        #pragma unroll 8
        for (int k = 0; k < 128; k += 2) {
            const float w0 = srow[k];
            const float w1 = srow[k + 1];
            const float2 v0 = *(const float2*)&KV[k * 36 + (d2 << 1)];
            const float2 v1 = *(const float2*)&KV[(k + 1) * 36 + (d2 << 1)];
            a00 = fmaf(w0, v0.x, a00); a01 = fmaf(w0, v0.y, a01);
            a10 = fmaf(w1, v1.x, a10); a11 = fmaf(w1, v1.y, a11);
        }
    }
    float2 o;
    o.x = (a00 + a10) * inv;
    o.y = (a01 + a11) * inv;
    *(float2*)&ctx[((size_t)(b * Nc + q0 + q)) * Dc + (h << 6) + (d2 << 1)] = o;
}

// ---------------------------------------------------------------------------
// Local attention (ef2 bf16)
// ---------------------------------------------------------------------------
__global__ __launch_bounds__(256) void local_scores(
    const float* __restrict__ qp, const float* __restrict__ kp,
    const ushort_t* __restrict__ ef2,
    const int* __restrict__ pb, const int* __restrict__ pi,
    const int* __restrict__ pj, float* __restrict__ sl)
{
    const int gid = blockIdx.x * 256 + threadIdx.x;   // e*8 + h
    const int h = gid & 7;
    const int e = gid >> 3;
    const int b = pb[e], i = pi[e], j = pj[e];
    const float* qrow = qp  + ((size_t)(b * Nc + i)) * Dc + (HHc + h) * DHc;
    const float* krow = kp  + ((size_t)(b * Nc + j)) * Dc + (HHc + h) * DHc;
    const ushort_t* erow = ef2 + (size_t)e * 256 + h * DHc;
    float s = 0.f;
    #pragma unroll
    for (int d4 = 0; d4 < 8; ++d4) {
        float4 qv = *(const float4*)&qrow[d4 << 2];
        float4 kv = *(const float4*)&krow[d4 << 2];
        ushort4 ev = *(const ushort4*)&erow[d4 << 2];
        s += qv.x * kv.x * bf2f(ev.x) + qv.y * kv.y * bf2f(ev.y)
           + qv.z * kv.z * bf2f(ev.z) + qv.w * kv.w * bf2f(ev.w);
    }
    sl[gid] = s * SCALE;
}

__global__ __launch_bounds__(256) void local_softmax(float* __restrict__ sl)
{
    const int gid = blockIdx.x * 256 + threadIdx.x;   // bi*8 + h
    const int h  = gid & 7;
    const int bi = gid >> 3;
    float s[DEGc];
    float m = -1e30f;
    #pragma unroll
    for (int tt = 0; tt < DEGc; ++tt) {
        s[tt] = sl[(size_t)(bi * DEGc + tt) * 8 + h];
        m = fmaxf(m, s[tt]);
    }
    float l = 0.f;
    #pragma unroll
    for (int tt = 0; tt < DEGc; ++tt) { s[tt] = expf(s[tt] - m); l += s[tt]; }
    const float inv = 1.0f / l;
    #pragma unroll
    for (int tt = 0; tt < DEGc; ++tt)
        sl[(size_t)(bi * DEGc + tt) * 8 + h] = s[tt] * inv;
}

__global__ __launch_bounds__(256) void local_ctx_kernel(
    const float* __restrict__ vp, const float* __restrict__ sl,
    const int* __restrict__ pj, float* __restrict__ ctx)
{
    const int bi = blockIdx.x;            // b*N + i
    const int t  = threadIdx.x;
    const int d  = t & 31;
    const int h  = t >> 5;
    __shared__ float a_s[DEGc][8];
    __shared__ int   jrow[DEGc];
    const int b = bi >> 9;
    if (t < DEGc) jrow[t] = pj[bi * DEGc + t];
    if (t < DEGc * 8) a_s[t >> 3][t & 7] = sl[(size_t)bi * (DEGc * 8) + t];
    __syncthreads();
    float acc = 0.f;
    #pragma unroll
    for (int tt = 0; tt < DEGc; ++tt) {
        const int j = jrow[tt];
        acc += a_s[tt][h] * vp[((size_t)(b * Nc + j)) * Dc + (HHc + h) * DHc + d];
    }
    ctx[(size_t)bi * Dc + (h << 6) + 32 + d] = acc;
}

// ---------------------------------------------------------------------------
extern "C" void kernel_launch(void* const* d_in, const int* in_sizes, int n_in,
                              void* d_out, int out_size, void* d_ws, size_t ws_size,
                              hipStream_t stream) {
    const float* key   = (const float*)d_in[0];
    const float* value = (const float*)d_in[1];
    const float* query = (const float*)d_in[2];
    const float* edge_feature = (const float*)d_in[4];
    const int* pb = (const int*)d_in[5];
    const int* pi = (const int*)d_in[6];
    const int* pj = (const int*)d_in[7];
    const float* Wq = (const float*)d_in[8];  const float* bq = (const float*)d_in[9];
    const float* Wk = (const float*)d_in[10]; const float* bk = (const float*)d_in[11];
    const float* Wv = (const float*)d_in[12]; const float* bv = (const float*)d_in[13];
    const float* Wo = (const float*)d_in[14]; const float* bo = (const float*)d_in[15];
    const float* We1 = (const float*)d_in[16]; const float* be1 = (const float*)d_in[17];
    const float* We2 = (const float*)d_in[18]; const float* be2 = (const float*)d_in[19];
    const float* Wu1 = (const float*)d_in[20]; const float* bu1 = (const float*)d_in[21];
    const float* Wu2 = (const float*)d_in[22]; const float* bu2 = (const float*)d_in[23];

    float* out  = (float*)d_out;          // (B,N,D)
    float* top  = out + 2097152;          // (B,N,N)
    float* eupd = out + 4194304;          // (E,D)

    float* qp  = (float*)d_ws;            // 2097152 f
    float* kp  = qp + 2097152;
    float* vp  = kp + 2097152;
    float* ctx = vp + 2097152;
    float* sl  = ctx + 2097152;           // 524288 f
    ushort_t* ef2b  = (ushort_t*)(sl + 524288);   // E*256
    ushort_t* efb   = ef2b + 16777216;            // E*512
    ushort_t* hidb  = efb + 33554432;             // E*512
    ushort_t* outb  = hidb + 33554432;            // 2097152
    ushort_t* wt_e1 = outb + 2097152;             // 512*512
    ushort_t* wt_e2 = wt_e1 + 262144;             // 256*512
    ushort_t* wt_u1 = wt_e2 + 131072;             // 512*1024 (two 512x512 halves)
    ushort_t* wt_u2 = wt_u1 + 524288;             // 512*512

    // Aliased into efb's region — efb is dead after the first edge-MLP GEMM,
    // and the edge path is launched FIRST (stream-serialized), so no overlap.
    ushort_t* wt_q = efb;                 // 262144
    ushort_t* wt_k = wt_q + 262144;
    ushort_t* wt_v = wt_k + 262144;
    ushort_t* wt_o = wt_v + 262144;
    ushort_t* qb   = wt_o + 262144;       // 2097152
    ushort_t* kb   = qb + 2097152;
    ushort_t* vb   = kb + 2097152;
    ushort_t* ctxb = vb + 2097152;        // ends at efb+9437184
    float* P1f = (float*)(ctxb + 2097152);   // 2097152 f (u1 partial, node i)
    float* P2f = P1f + 2097152;              // 2097152 f — ends < efb+33554432 ok

    dim3 blk(256);
    dim3 tblk(32, 8);

    // ---- Edge path first (frees efb for aliasing) ----
    transpose_cvt<<<dim3(16, 16), tblk, 0, stream>>>(We1, wt_e1, 512, 512);
    transpose_cvt<<<dim3(16, 8),  tblk, 0, stream>>>(We2, wt_e2, 512, 256);
    // Wu1 split into top (k<512) / bottom (k>=512) halves, each 512x512
    transpose_cvt<<<dim3(16, 16), tblk, 0, stream>>>(Wu1, wt_u1, 512, 512);
    transpose_cvt<<<dim3(16, 16), tblk, 0, stream>>>(Wu1 + 512 * 512, wt_u1 + 262144, 512, 512);
    transpose_cvt<<<dim3(16, 16), tblk, 0, stream>>>(Wu2, wt_u2, 512, 512);
    cvt_f32_bf16<<<32768, blk, 0, stream>>>(edge_feature, efb);

    // Edge MLP (bf16 MFMA): hid = act(ef @ We1 + be1); ef2 = hid @ We2 + be2
    gemm_mfma<1, 0, 1, 512, 512><<<dim3(4, 512), blk, 0, stream>>>(efb, wt_e1, be1, hidb, nullptr, nullptr, nullptr, nullptr);
    gemm_mfma<0, 0, 1, 512, 256><<<dim3(2, 512), blk, 0, stream>>>(hidb, wt_e2, be2, ef2b, nullptr, nullptr, nullptr, nullptr);
    // efb dead from here on.

    // ---- QKV projections on the matrix pipe ----
    transpose_cvt<<<dim3(16, 16), tblk, 0, stream>>>(Wq, wt_q, 512, 512);
    transpose_cvt<<<dim3(16, 16), tblk, 0, stream>>>(Wk, wt_k, 512, 512);
    transpose_cvt<<<dim3(16, 16), tblk, 0, stream>>>(Wv, wt_v, 512, 512);
    transpose_cvt<<<dim3(16, 16), tblk, 0, stream>>>(Wo, wt_o, 512, 512);
    cvt_f32_bf16<<<2048, blk, 0, stream>>>(query, qb);
    cvt_f32_bf16<<<2048, blk, 0, stream>>>(key,   kb);
    cvt_f32_bf16<<<2048, blk, 0, stream>>>(value, vb);

    gemm_mfma<0, 0, 0, 512, 512><<<dim3(4, 32), blk, 0, stream>>>(qb, wt_q, bq, qp, nullptr, nullptr, nullptr, nullptr);
    gemm_mfma<0, 0, 0, 512, 512><<<dim3(4, 32), blk, 0, stream>>>(kb, wt_k, bk, kp, nullptr, nullptr, nullptr, nullptr);
    gemm_mfma<0, 0, 0, 512, 512><<<dim3(4, 32), blk, 0, stream>>>(vb, wt_v, bv, vp, nullptr, nullptr, nullptr, nullptr);

    // ---- Attention ----
    global_attn<<<dim3(32, 64), blk, 0, stream>>>(qp, kp, vp, ctx, top);
    local_scores<<<2048, blk, 0, stream>>>(qp, kp, ef2b, pb, pi, pj, sl);
    local_softmax<<<128, blk, 0, stream>>>(sl);
    local_ctx_kernel<<<4096, blk, 0, stream>>>(vp, sl, pj, ctx);

    // ---- Output projection (bf16 MFMA, writes fp32 out + bf16 outb) ----
    cvt_f32_bf16<<<2048, blk, 0, stream>>>(ctx, ctxb);
    gemm_mfma<0, 0, 2, 512, 512><<<dim3(4, 32), blk, 0, stream>>>(ctxb, wt_o, bo, out, outb, nullptr, nullptr, nullptr);

    // ---- Edge update MLP via linearity split (no gathered 68.7-GF GEMM):
    //      P1 = out@Wu1_top, P2 = out@Wu1_bot (fp32, no bias);
    //      hid = bf16(softplus(P1[i] + P2[j] + bu1) - ln2);  eupd = hid@Wu2+bu2
    gemm_mfma<0, 0, 0, 512, 512, 0><<<dim3(4, 32), blk, 0, stream>>>(outb, wt_u1, bu1, P1f, nullptr, nullptr, nullptr, nullptr);
    gemm_mfma<0, 0, 0, 512, 512, 0><<<dim3(4, 32), blk, 0, stream>>>(outb, wt_u1 + 262144, bu1, P2f, nullptr, nullptr, nullptr, nullptr);
    edge_u1_fuse<<<32768, blk, 0, stream>>>(P1f, P2f, bu1, pb, pi, pj, hidb);
    gemm_mfma<0, 0, 0, 512, 512><<<dim3(4, 512), blk, 0, stream>>>(hidb, wt_u2, bu2, eupd, nullptr, nullptr, nullptr, nullptr);
}

// Round 7
// 643.032 us; speedup vs baseline: 1.1724x; 1.0838x over previous
//
#include <hip/hip_runtime.h>
#include <math.h>

// Problem constants (fixed by reference)
constexpr int Bc   = 8;
constexpr int Nc   = 512;
constexpr int Dc   = 512;
constexpr int HHc  = 8;     // half the heads
constexpr int DHc  = 32;
constexpr int DEGc = 16;
constexpr int Ec   = Bc * Nc * DEGc;          // 65536 edges
constexpr float LN2   = 0.69314718055994530942f;
constexpr float SCALE = 0.17677669529663688110f;  // 1/sqrt(32)

typedef unsigned short ushort_t;
typedef __attribute__((ext_vector_type(8))) short short8;
typedef __attribute__((ext_vector_type(4))) float f32x4;

// softplus(x)-ln2 via native v_exp_f32/v_log_f32 (~7 VALU inst)
__device__ __forceinline__ float splus_m_ln2(float x) {
    float t = __expf(-fabsf(x));
    return fmaxf(x, 0.0f) + __logf(1.0f + t) - LN2;
}

__device__ __forceinline__ ushort_t f2bf(float x) {
    union { float f; unsigned int u; } v; v.f = x;
    unsigned int r = (v.u + 0x7fffu + ((v.u >> 16) & 1u)) >> 16;   // RNE
    return (ushort_t)r;
}
__device__ __forceinline__ float bf2f(ushort_t x) {
    union { unsigned int u; float f; } v; v.u = ((unsigned int)x) << 16;
    return v.f;
}

__device__ __forceinline__ void gload16(const ushort_t* g, ushort_t* l) {
    __builtin_amdgcn_global_load_lds(
        (const __attribute__((address_space(1))) void*)g,
        (__attribute__((address_space(3))) void*)l, 16, 0, 0);
}

// ---------------------------------------------------------------------------
// bf16 MFMA GEMM: C[M,NOUT] = act(A[M,K] @ Bt^T + bias)
// 3-buffer pipeline, counted vmcnt (T4); T2 both-sides XOR swizzle.
// OUTMODE: 0 = fp32 out, 1 = bf16 out, 2 = fp32 out + bf16 copy to Cout2
// BIAS: 0 = skip bias add. 128x128 tile, BK=32, 4 waves 2x2. LDS 48 KB.
// ---------------------------------------------------------------------------
template<int ACT, int GATHER, int OUTMODE, int K, int NOUT, int BIAS = 1>
__global__ __launch_bounds__(256) void gemm_mfma(
    const ushort_t* __restrict__ A, const ushort_t* __restrict__ Bt,
    const float* __restrict__ bias, void* __restrict__ Cout,
    ushort_t* __restrict__ Cout2,
    const int* __restrict__ pb, const int* __restrict__ pi,
    const int* __restrict__ pj)
{
    __shared__ ushort_t As[3][128 * 32];
    __shared__ ushort_t Bs[3][128 * 32];

    const int t    = threadIdx.x;
    const int lane = t & 63;
    const int w    = t >> 6;
    const int wy   = w >> 1, wx = w & 1;
    const int rowBase = blockIdx.y * 128;
    const int colBase = blockIdx.x * 128;

    const int sm0  = t >> 2;
    const int kchs = (((t & 3) ^ ((t >> 2) & 3)) << 3);   // swizzled src chunk

    const ushort_t *a0i, *a0j = nullptr, *a1i, *a1j = nullptr;
    if (GATHER) {
        const int e0 = rowBase + sm0, e1 = rowBase + 64 + sm0;
        a0i = A + ((size_t)(pb[e0] * Nc + pi[e0])) * Dc;
        a0j = A + ((size_t)(pb[e0] * Nc + pj[e0])) * Dc;
        a1i = A + ((size_t)(pb[e1] * Nc + pi[e1])) * Dc;
        a1j = A + ((size_t)(pb[e1] * Nc + pj[e1])) * Dc;
    } else {
        a0i = A + (size_t)(rowBase + sm0) * K;
        a1i = A + (size_t)(rowBase + 64 + sm0) * K;
    }
    const ushort_t* b0 = Bt + (size_t)(colBase + sm0) * K;
    const ushort_t* b1 = Bt + (size_t)(colBase + 64 + sm0) * K;

    const int soff0 = w * 64 * 8;
    const int soff1 = (256 + w * 64) * 8;

    f32x4 acc[4][4];
    const f32x4 fz = {0.f, 0.f, 0.f, 0.f};
    #pragma unroll
    for (int i = 0; i < 4; ++i)
        #pragma unroll
        for (int j = 0; j < 4; ++j) acc[i][j] = fz;

    const int c16 = lane & 15;
    const int q16 = lane >> 4;
    const int rdo = ((q16 ^ (c16 & 3)) << 3);   // swizzled read chunk offset

    auto STAGE = [&](int s, int kb) {
        const int k0 = kb << 5;
        const ushort_t *pa0, *pa1;
        if constexpr (GATHER) {
            if (kb < (Dc >> 5)) { pa0 = a0i + k0; pa1 = a1i + k0; }
            else                { pa0 = a0j + (k0 - Dc); pa1 = a1j + (k0 - Dc); }
        } else { pa0 = a0i + k0; pa1 = a1i + k0; }
        gload16(pa0 + kchs, &As[s][soff0]);
        gload16(pa1 + kchs, &As[s][soff1]);
        gload16(b0 + k0 + kchs, &Bs[s][soff0]);
        gload16(b1 + k0 + kchs, &Bs[s][soff1]);
    };

    auto COMPUTE = [&](int s) {
        short8 af[4], bfr[4];
        #pragma unroll
        for (int i = 0; i < 4; ++i)
            af[i] = *(const short8*)&As[s][(size_t)((wy * 64 + i * 16 + c16) * 32 + rdo)];
        #pragma unroll
        for (int j = 0; j < 4; ++j)
            bfr[j] = *(const short8*)&Bs[s][(size_t)((wx * 64 + j * 16 + c16) * 32 + rdo)];
        #pragma unroll
        for (int i = 0; i < 4; ++i)
            #pragma unroll
            for (int j = 0; j < 4; ++j)
                acc[i][j] = __builtin_amdgcn_mfma_f32_16x16x32_bf16(af[i], bfr[j], acc[i][j], 0, 0, 0);
    };

    constexpr int NKB = K >> 5;
    STAGE(0, 0);
    STAGE(1, 1);
    for (int kb = 0; kb < NKB - 2; ++kb) {
        asm volatile("s_waitcnt vmcnt(4)" ::: "memory");
        __builtin_amdgcn_s_barrier();
        STAGE((kb + 2) % 3, kb + 2);
        COMPUTE(kb % 3);
    }
    asm volatile("s_waitcnt vmcnt(4)" ::: "memory");
    __builtin_amdgcn_s_barrier();
    COMPUTE((NKB - 2) % 3);
    asm volatile("s_waitcnt vmcnt(0)" ::: "memory");
    __builtin_amdgcn_s_barrier();
    COMPUTE((NKB - 1) % 3);

    // Epilogue: C/D layout col=lane&15, row=(lane>>4)*4+reg  [m89-verified]
    #pragma unroll
    for (int j = 0; j < 4; ++j) {
        const int col = colBase + wx * 64 + j * 16 + c16;
        const float bv = BIAS ? bias[col] : 0.0f;
        #pragma unroll
        for (int i = 0; i < 4; ++i) {
            const int row0 = rowBase + wy * 64 + i * 16 + q16 * 4;
            #pragma unroll
            for (int r = 0; r < 4; ++r) {
                float v = acc[i][j][r] + bv;
                if (ACT) v = splus_m_ln2(v);
                const size_t idx = (size_t)(row0 + r) * NOUT + col;
                if (OUTMODE == 1) {
                    ((ushort_t*)Cout)[idx] = f2bf(v);
                } else {
                    ((float*)Cout)[idx] = v;
                    if (OUTMODE == 2) Cout2[idx] = f2bf(v);
                }
            }
        }
    }
}

// ---------------------------------------------------------------------------
// Edge-update fuse: hid[e] = bf16(softplus(P1[b,i] + P2[b,j] + bu1) - ln2)
// ---------------------------------------------------------------------------
__global__ __launch_bounds__(256) void edge_u1_fuse(
    const float* __restrict__ P1, const float* __restrict__ P2,
    const float* __restrict__ bias,
    const int* __restrict__ pb, const int* __restrict__ pi,
    const int* __restrict__ pj, ushort_t* __restrict__ hid)
{
    const int e  = blockIdx.x * 2 + (threadIdx.x >> 7);
    const int c4 = (threadIdx.x & 127) << 2;
    const int b = pb[e], i = pi[e], j = pj[e];
    const float4 a = *(const float4*)&P1[((size_t)(b * Nc + i)) * Dc + c4];
    const float4 d = *(const float4*)&P2[((size_t)(b * Nc + j)) * Dc + c4];
    const float4 bv = *(const float4*)&bias[c4];
    ushort4 o;
    o.x = f2bf(splus_m_ln2(a.x + d.x + bv.x));
    o.y = f2bf(splus_m_ln2(a.y + d.y + bv.y));
    o.z = f2bf(splus_m_ln2(a.z + d.z + bv.z));
    o.w = f2bf(splus_m_ln2(a.w + d.w + bv.w));
    *(ushort4*)&hid[(size_t)e * Dc + c4] = o;
}

// ---------------------------------------------------------------------------
// Conversion helpers
// ---------------------------------------------------------------------------
__global__ __launch_bounds__(256) void cvt_f32_bf16(
    const float* __restrict__ src, ushort_t* __restrict__ dst)
{
    const int i = blockIdx.x * 256 + threadIdx.x;
    float4 v = ((const float4*)src)[i];
    ushort4 o;
    o.x = f2bf(v.x); o.y = f2bf(v.y); o.z = f2bf(v.z); o.w = f2bf(v.w);
    ((ushort4*)dst)[i] = o;
}

// Wt[n][k] = bf16(W[k][n]); block (32,8), one 32x32 tile per block
__global__ void transpose_cvt(const float* __restrict__ W, ushort_t* __restrict__ Wt,
                              int K, int NOUT)
{
    __shared__ float tile[32][33];
    const int k0 = blockIdx.x * 32, n0 = blockIdx.y * 32;
    #pragma unroll
    for (int r = 0; r < 4; ++r)
        tile[threadIdx.y + r * 8][threadIdx.x] =
            W[(size_t)(k0 + threadIdx.y + r * 8) * NOUT + n0 + threadIdx.x];
    __syncthreads();
    #pragma unroll
    for (int r = 0; r < 4; ++r)
        Wt[(size_t)(n0 + threadIdx.y + r * 8) * K + k0 + threadIdx.x] =
            f2bf(tile[threadIdx.x][threadIdx.y + r * 8]);
}

// vtb[(b*8+h)][d][n] = bf16(vp[b*N+n][h*32+d])  — per-global-head V transpose
__global__ void vt_prep(const float* __restrict__ vp, ushort_t* __restrict__ vtb)
{
    __shared__ float tile[32][33];
    const int n0 = blockIdx.x * 32;
    const int bh = blockIdx.y;
    const int b = bh >> 3, h = bh & 7;
    #pragma unroll
    for (int r = 0; r < 4; ++r)
        tile[threadIdx.y + r * 8][threadIdx.x] =
            vp[((size_t)(b * Nc + n0 + threadIdx.y + r * 8)) * Dc + h * DHc + threadIdx.x];
    __syncthreads();
    #pragma unroll
    for (int r = 0; r < 4; ++r)
        vtb[((size_t)bh * DHc + threadIdx.y + r * 8) * Nc + n0 + threadIdx.x] =
            f2bf(tile[threadIdx.x][threadIdx.y + r * 8]);
}

// ---------------------------------------------------------------------------
// Global attention, MFMA flash-style.
// Grid (8, 64): block = 256 thr = 4 waves; wave owns 16 q rows of one (b,h).
// Per 32-k chunk: QK^T = 2x mfma_16x16x32 (Q,K frags direct from global bf16;
// KV is L2-resident — no LDS staging, no barriers). Online softmax in fp32
// registers. P -> bf16 via wave-private LDS round-trip into A-frag layout;
// PV = 2x mfma against pre-transposed V (vtb). top written from fp32 accums
// (h==0) through a per-wave LDS coalescing buffer.
// Frag layouts (verified via the working GEMM): A/B lane l holds
// [row=l&15][k=(l>>4)*8+j]; C/D: col=l&15, row=(l>>4)*4+r.
// ---------------------------------------------------------------------------
__global__ __launch_bounds__(256) void global_attn(
    const ushort_t* __restrict__ qb16, const ushort_t* __restrict__ kb16,
    const ushort_t* __restrict__ vtb,
    float* __restrict__ ctx, float* __restrict__ top)
{
    __shared__ ushort_t Plds[4][16 * 40];   // P, row stride 40 (bank spread)
    __shared__ float    stb[4][16 * 36];    // coalesce buffer (top / ctx out)

    const int t    = threadIdx.x;
    const int wv   = t >> 6;
    const int lane = t & 63;
    const int c16  = lane & 15;
    const int g    = lane >> 4;
    const int bh   = blockIdx.y;
    const int b    = bh >> 3;
    const int h    = bh & (HHc - 1);
    const int q0   = blockIdx.x * 64 + wv * 16;
    const bool htop = (h == 0);

    const f32x4 fz = {0.f, 0.f, 0.f, 0.f};

    // Q fragment: lane holds Q[q0 + c16][g*8 .. g*8+7] of this head
    const short8 qf = *(const short8*)
        &qb16[((size_t)(b * Nc + q0 + c16)) * Dc + h * DHc + g * 8];
    const ushort_t* kbase  = kb16 + ((size_t)b * Nc) * Dc + h * DHc + g * 8;
    const ushort_t* vbase0 = vtb + ((size_t)(bh * DHc) + c16) * Nc + g * 8;
    const ushort_t* vbase1 = vbase0 + (size_t)16 * Nc;
    ushort_t* Pw = Plds[wv];
    float*    sw = stb[wv];

    float m[4]   = {-1e30f, -1e30f, -1e30f, -1e30f};
    float ell[4] = {0.f, 0.f, 0.f, 0.f};
    f32x4 o0 = fz, o1 = fz;

    const int ql = lane >> 2;          // coalesced-writer row
    const int c8 = (lane & 3) << 3;    // coalesced-writer col offset

    for (int k0 = 0; k0 < Nc; k0 += 32) {
        // ---- QK^T: scores for 16q x 32k, fp32 accum ----
        const short8 kf0 = *(const short8*)&kbase[(size_t)(k0 + c16) * Dc];
        const short8 kf1 = *(const short8*)&kbase[(size_t)(k0 + 16 + c16) * Dc];
        f32x4 s0 = __builtin_amdgcn_mfma_f32_16x16x32_bf16(qf, kf0, fz, 0, 0, 0);
        f32x4 s1 = __builtin_amdgcn_mfma_f32_16x16x32_bf16(qf, kf1, fz, 0, 0, 0);
        #pragma unroll
        for (int r = 0; r < 4; ++r) { s0[r] *= SCALE; s1[r] *= SCALE; }

        // ---- top (h==0): fp32 scores via LDS coalesce ----
        if (htop) {
            #pragma unroll
            for (int r = 0; r < 4; ++r) {
                const int q = g * 4 + r;
                sw[q * 36 + c16]      = s0[r];
                sw[q * 36 + 16 + c16] = s1[r];
            }
            float* trow = top + ((size_t)(b * Nc + q0 + ql)) * Nc + k0 + c8;
            *(float4*)trow       = *(const float4*)&sw[ql * 36 + c8];
            *(float4*)(trow + 4) = *(const float4*)&sw[ql * 36 + c8 + 4];
        }

        // ---- online softmax (per q-row: 16-lane shfl reduce) ----
        #pragma unroll
        for (int r = 0; r < 4; ++r) {
            float tm = fmaxf(s0[r], s1[r]);
            #pragma unroll
            for (int mk = 1; mk < 16; mk <<= 1)
                tm = fmaxf(tm, __shfl_xor(tm, mk, 64));
            const float nm = fmaxf(m[r], tm);
            const float fs = __expf(m[r] - nm);
            m[r] = nm;
            const float p0 = __expf(s0[r] - nm);
            const float p1 = __expf(s1[r] - nm);
            float es = p0 + p1;
            #pragma unroll
            for (int mk = 1; mk < 16; mk <<= 1)
                es += __shfl_xor(es, mk, 64);
            ell[r] = ell[r] * fs + es;
            o0[r] *= fs; o1[r] *= fs;
            s0[r] = p0; s1[r] = p1;
        }

        // ---- P -> bf16, redistribute to A-frag layout via wave-private LDS
        #pragma unroll
        for (int r = 0; r < 4; ++r) {
            const int q = g * 4 + r;
            Pw[q * 40 + c16]      = f2bf(s0[r]);
            Pw[q * 40 + 16 + c16] = f2bf(s1[r]);
        }
        const short8 pf = *(const short8*)&Pw[c16 * 40 + g * 8];

        // ---- PV: O += P @ V  (Vt rows = d, content = k) ----
        const short8 v0 = *(const short8*)&vbase0[k0];
        const short8 v1 = *(const short8*)&vbase1[k0];
        o0 = __builtin_amdgcn_mfma_f32_16x16x32_bf16(pf, v0, o0, 0, 0, 0);
        o1 = __builtin_amdgcn_mfma_f32_16x16x32_bf16(pf, v1, o1, 0, 0, 0);
    }

    // ---- normalize and write ctx (global half: cols h*64 .. h*64+31) ----
    #pragma unroll
    for (int r = 0; r < 4; ++r) {
        const float inv = 1.0f / ell[r];
        const int q = g * 4 + r;
        sw[q * 36 + c16]      = o0[r] * inv;
        sw[q * 36 + 16 + c16] = o1[r] * inv;
    }
    float* crow = ctx + ((size_t)(b * Nc + q0 + ql)) * Dc + (h << 6) + c8;
    *(float4*)crow       = *(const float4*)&sw[ql * 36 + c8];
    *(float4*)(crow + 4) = *(const float4*)&sw[ql * 36 + c8 + 4];
}

// ---------------------------------------------------------------------------
// Local attention (ef2 bf16)
// ---------------------------------------------------------------------------
__global__ __launch_bounds__(256) void local_scores(
    const float* __restrict__ qp, const float* __restrict__ kp,
    const ushort_t* __restrict__ ef2,
    const int* __restrict__ pb, const int* __restrict__ pi,
    const int* __restrict__ pj, float* __restrict__ sl)
{
    const int gid = blockIdx.x * 256 + threadIdx.x;   // e*8 + h
    const int h = gid & 7;
    const int e = gid >> 3;
    const int b = pb[e], i = pi[e], j = pj[e];
    const float* qrow = qp  + ((size_t)(b * Nc + i)) * Dc + (HHc + h) * DHc;
    const float* krow = kp  + ((size_t)(b * Nc + j)) * Dc + (HHc + h) * DHc;
    const ushort_t* erow = ef2 + (size_t)e * 256 + h * DHc;
    float s = 0.f;
    #pragma unroll
    for (int d4 = 0; d4 < 8; ++d4) {
        float4 qv = *(const float4*)&qrow[d4 << 2];
        float4 kv = *(const float4*)&krow[d4 << 2];
        ushort4 ev = *(const ushort4*)&erow[d4 << 2];
        s += qv.x * kv.x * bf2f(ev.x) + qv.y * kv.y * bf2f(ev.y)
           + qv.z * kv.z * bf2f(ev.z) + qv.w * kv.w * bf2f(ev.w);
    }
    sl[gid] = s * SCALE;
}

__global__ __launch_bounds__(256) void local_softmax(float* __restrict__ sl)
{
    const int gid = blockIdx.x * 256 + threadIdx.x;   // bi*8 + h
    const int h  = gid & 7;
    const int bi = gid >> 3;
    float s[DEGc];
    float m = -1e30f;
    #pragma unroll
    for (int tt = 0; tt < DEGc; ++tt) {
        s[tt] = sl[(size_t)(bi * DEGc + tt) * 8 + h];
        m = fmaxf(m, s[tt]);
    }
    float l = 0.f;
    #pragma unroll
    for (int tt = 0; tt < DEGc; ++tt) { s[tt] = expf(s[tt] - m); l += s[tt]; }
    const float inv = 1.0f / l;
    #pragma unroll
    for (int tt = 0; tt < DEGc; ++tt)
        sl[(size_t)(bi * DEGc + tt) * 8 + h] = s[tt] * inv;
}

__global__ __launch_bounds__(256) void local_ctx_kernel(
    const float* __restrict__ vp, const float* __restrict__ sl,
    const int* __restrict__ pj, float* __restrict__ ctx)
{
    const int bi = blockIdx.x;            // b*N + i
    const int t  = threadIdx.x;
    const int d  = t & 31;
    const int h  = t >> 5;
    __shared__ float a_s[DEGc][8];
    __shared__ int   jrow[DEGc];
    const int b = bi >> 9;
    if (t < DEGc) jrow[t] = pj[bi * DEGc + t];
    if (t < DEGc * 8) a_s[t >> 3][t & 7] = sl[(size_t)bi * (DEGc * 8) + t];
    __syncthreads();
    float acc = 0.f;
    #pragma unroll
    for (int tt = 0; tt < DEGc; ++tt) {
        const int j = jrow[tt];
        acc += a_s[tt][h] * vp[((size_t)(b * Nc + j)) * Dc + (HHc + h) * DHc + d];
    }
    ctx[(size_t)bi * Dc + (h << 6) + 32 + d] = acc;
}

// ---------------------------------------------------------------------------
extern "C" void kernel_launch(void* const* d_in, const int* in_sizes, int n_in,
                              void* d_out, int out_size, void* d_ws, size_t ws_size,
                              hipStream_t stream) {
    const float* key   = (const float*)d_in[0];
    const float* value = (const float*)d_in[1];
    const float* query = (const float*)d_in[2];
    const float* edge_feature = (const float*)d_in[4];
    const int* pb = (const int*)d_in[5];
    const int* pi = (const int*)d_in[6];
    const int* pj = (const int*)d_in[7];
    const float* Wq = (const float*)d_in[8];  const float* bq = (const float*)d_in[9];
    const float* Wk = (const float*)d_in[10]; const float* bk = (const float*)d_in[11];
    const float* Wv = (const float*)d_in[12]; const float* bv = (const float*)d_in[13];
    const float* Wo = (const float*)d_in[14]; const float* bo = (const float*)d_in[15];
    const float* We1 = (const float*)d_in[16]; const float* be1 = (const float*)d_in[17];
    const float* We2 = (const float*)d_in[18]; const float* be2 = (const float*)d_in[19];
    const float* Wu1 = (const float*)d_in[20]; const float* bu1 = (const float*)d_in[21];
    const float* Wu2 = (const float*)d_in[22]; const float* bu2 = (const float*)d_in[23];

    float* out  = (float*)d_out;          // (B,N,D)
    float* top  = out + 2097152;          // (B,N,N)
    float* eupd = out + 4194304;          // (E,D)

    float* qp  = (float*)d_ws;            // 2097152 f
    float* kp  = qp + 2097152;
    float* vp  = kp + 2097152;
    float* ctx = vp + 2097152;
    float* sl  = ctx + 2097152;           // 524288 f
    ushort_t* ef2b  = (ushort_t*)(sl + 524288);   // E*256
    ushort_t* efb   = ef2b + 16777216;            // E*512
    ushort_t* hidb  = efb + 33554432;             // E*512
    ushort_t* outb  = hidb + 33554432;            // 2097152
    ushort_t* wt_e1 = outb + 2097152;             // 512*512
    ushort_t* wt_e2 = wt_e1 + 262144;             // 256*512
    ushort_t* wt_u1 = wt_e2 + 131072;             // 512*1024 (two 512x512 halves)
    ushort_t* wt_u2 = wt_u1 + 524288;             // 512*512

    // Aliased into efb's region — efb is dead after the first edge-MLP GEMM,
    // and the edge path is launched FIRST (stream-serialized), so no overlap.
    ushort_t* wt_q = efb;                 // 262144
    ushort_t* wt_k = wt_q + 262144;
    ushort_t* wt_v = wt_k + 262144;
    ushort_t* wt_o = wt_v + 262144;
    ushort_t* qb   = wt_o + 262144;       // 2097152
    ushort_t* kb   = qb + 2097152;
    ushort_t* vb   = kb + 2097152;
    ushort_t* ctxb = vb + 2097152;        // ends at efb+9437184
    float* P1f = (float*)(ctxb + 2097152);   // 2097152 f (u1 partial, node i)
    float* P2f = P1f + 2097152;              // 2097152 f — ends at efb+17825792 ush
    ushort_t* qb16 = (ushort_t*)(P2f + 2097152);  // 2097152 (bf16 of qp)
    ushort_t* kb16 = qb16 + 2097152;              // 2097152 (bf16 of kp)
    ushort_t* vtb  = kb16 + 2097152;              // 1048576 (V^T per global head)
    // ends at efb+23068672 < efb+33554432  ok

    dim3 blk(256);
    dim3 tblk(32, 8);

    // ---- Edge path first (frees efb for aliasing) ----
    transpose_cvt<<<dim3(16, 16), tblk, 0, stream>>>(We1, wt_e1, 512, 512);
    transpose_cvt<<<dim3(16, 8),  tblk, 0, stream>>>(We2, wt_e2, 512, 256);
    transpose_cvt<<<dim3(16, 16), tblk, 0, stream>>>(Wu1, wt_u1, 512, 512);
    transpose_cvt<<<dim3(16, 16), tblk, 0, stream>>>(Wu1 + 512 * 512, wt_u1 + 262144, 512, 512);
    transpose_cvt<<<dim3(16, 16), tblk, 0, stream>>>(Wu2, wt_u2, 512, 512);
    cvt_f32_bf16<<<32768, blk, 0, stream>>>(edge_feature, efb);

    // Edge MLP (bf16 MFMA): hid = act(ef @ We1 + be1); ef2 = hid @ We2 + be2
    gemm_mfma<1, 0, 1, 512, 512><<<dim3(4, 512), blk, 0, stream>>>(efb, wt_e1, be1, hidb, nullptr, nullptr, nullptr, nullptr);
    gemm_mfma<0, 0, 1, 512, 256><<<dim3(2, 512), blk, 0, stream>>>(hidb, wt_e2, be2, ef2b, nullptr, nullptr, nullptr, nullptr);
    // efb dead from here on.

    // ---- QKV projections (q,k also emit bf16 copies for MFMA attention) ----
    transpose_cvt<<<dim3(16, 16), tblk, 0, stream>>>(Wq, wt_q, 512, 512);
    transpose_cvt<<<dim3(16, 16), tblk, 0, stream>>>(Wk, wt_k, 512, 512);
    transpose_cvt<<<dim3(16, 16), tblk, 0, stream>>>(Wv, wt_v, 512, 512);
    transpose_cvt<<<dim3(16, 16), tblk, 0, stream>>>(Wo, wt_o, 512, 512);
    cvt_f32_bf16<<<2048, blk, 0, stream>>>(query, qb);
    cvt_f32_bf16<<<2048, blk, 0, stream>>>(key,   kb);
    cvt_f32_bf16<<<2048, blk, 0, stream>>>(value, vb);

    gemm_mfma<0, 0, 2, 512, 512><<<dim3(4, 32), blk, 0, stream>>>(qb, wt_q, bq, qp, qb16, nullptr, nullptr, nullptr);
    gemm_mfma<0, 0, 2, 512, 512><<<dim3(4, 32), blk, 0, stream>>>(kb, wt_k, bk, kp, kb16, nullptr, nullptr, nullptr);
    gemm_mfma<0, 0, 0, 512, 512><<<dim3(4, 32), blk, 0, stream>>>(vb, wt_v, bv, vp, nullptr, nullptr, nullptr, nullptr);
    vt_prep<<<dim3(16, 64), tblk, 0, stream>>>(vp, vtb);

    // ---- Attention ----
    global_attn<<<dim3(8, 64), blk, 0, stream>>>(qb16, kb16, vtb, ctx, top);
    local_scores<<<2048, blk, 0, stream>>>(qp, kp, ef2b, pb, pi, pj, sl);
    local_softmax<<<128, blk, 0, stream>>>(sl);
    local_ctx_kernel<<<4096, blk, 0, stream>>>(vp, sl, pj, ctx);

    // ---- Output projection (bf16 MFMA, writes fp32 out + bf16 outb) ----
    cvt_f32_bf16<<<2048, blk, 0, stream>>>(ctx, ctxb);
    gemm_mfma<0, 0, 2, 512, 512><<<dim3(4, 32), blk, 0, stream>>>(ctxb, wt_o, bo, out, outb, nullptr, nullptr, nullptr);

    // ---- Edge update MLP via linearity split:
    //      P1 = out@Wu1_top, P2 = out@Wu1_bot (fp32, no bias);
    //      hid = bf16(softplus(P1[i] + P2[j] + bu1) - ln2);  eupd = hid@Wu2+bu2
    gemm_mfma<0, 0, 0, 512, 512, 0><<<dim3(4, 32), blk, 0, stream>>>(outb, wt_u1, bu1, P1f, nullptr, nullptr, nullptr, nullptr);
    gemm_mfma<0, 0, 0, 512, 512, 0><<<dim3(4, 32), blk, 0, stream>>>(outb, wt_u1 + 262144, bu1, P2f, nullptr, nullptr, nullptr, nullptr);
    edge_u1_fuse<<<32768, blk, 0, stream>>>(P1f, P2f, bu1, pb, pi, pj, hidb);
    gemm_mfma<0, 0, 0, 512, 512><<<dim3(4, 512), blk, 0, stream>>>(hidb, wt_u2, bu2, eupd, nullptr, nullptr, nullptr, nullptr);
}